// Round 2
// 97.683 us; speedup vs baseline: 1.0096x; 1.0096x over previous
//
#include <hip/hip_runtime.h>
#include <math.h>

#define KCOMP 16
#define DDIM 8
#define CSTRIDE 48   // 36 A + 8 b + 1 const + 3 pad; 192 B per component (16B-aligned rows)
#define PPT 4        // points per thread: 1024 blocks -> 4 blocks/CU -> 4 waves/SIMD

// Coefficient table lives in a module-scope device global (3 KB): no workspace
// dependence (defends against null/undersized d_ws, which can hard-kill the
// container), no hipMalloc, no graph-capture hazard. gmm_setup rebuilds it
// every launch so fresh inputs are always honored.
__device__ float g_tab[KCOMP * CSTRIDE];

// ---------------------------------------------------------------------------
// Kernel 1 (one tiny block): build the coefficient table.
//   A'_k = L_k^{-1}/sqrt2 (36 tril), b'_k = -A'_k mu_k (8),
//   slot44 = const_k - Cmax (exp offset pre-folded), slot45 = Cmax.
// Kernel 2 (1024 blocks x 256): load 3KB table into LDS, evaluate 4 pts/thread:
//   lp_k = ck - ||A'x + b'||^2 ; out = Cmax + log(sum_k exp(lp_k))
// Splitting setup out of the hot kernel removes ~200 VGPRs of cold-path
// pressure (Lc/C/L/Li arrays) so the eval kernel fits 4 blocks/CU at <=128 VGPR.
// ---------------------------------------------------------------------------
__global__ __launch_bounds__(64) void gmm_setup(const float* __restrict__ means,
                                                const float* __restrict__ chol_var,
                                                const float* __restrict__ pi) {
    __shared__ float sconst[KCOMP];
    const int k = threadIdx.x;
    if (k < KCOMP) {
        // Lc = tril(chol_var[k])
        float Lc[DDIM][DDIM];
#pragma unroll
        for (int i = 0; i < DDIM; ++i)
#pragma unroll
            for (int j = 0; j < DDIM; ++j)
                Lc[i][j] = (j <= i) ? chol_var[k * DDIM * DDIM + i * DDIM + j] : 0.0f;

        // cov = Lc Lc^T + eps I (lower part only)
        float C[DDIM][DDIM];
#pragma unroll
        for (int i = 0; i < DDIM; ++i)
#pragma unroll
            for (int j = 0; j <= i; ++j) {
                float s = 0.0f;
#pragma unroll
                for (int m = 0; m < DDIM; ++m) s += Lc[i][m] * Lc[j][m];
                C[i][j] = s;
            }
#pragma unroll
        for (int i = 0; i < DDIM; ++i) C[i][i] += 1e-6f;

        // Cholesky: C = L L^T
        float L[DDIM][DDIM];
#pragma unroll
        for (int j = 0; j < DDIM; ++j) {
            float d = C[j][j];
#pragma unroll
            for (int m = 0; m < DDIM; ++m) if (m < j) d -= L[j][m] * L[j][m];
            float ljj = sqrtf(d);
            L[j][j] = ljj;
            float inv = 1.0f / ljj;
#pragma unroll
            for (int i = 0; i < DDIM; ++i) {
                if (i <= j) continue;
                float s = C[i][j];
#pragma unroll
                for (int m = 0; m < DDIM; ++m) if (m < j) s -= L[i][m] * L[j][m];
                L[i][j] = s * inv;
            }
        }

        // Li = L^{-1} (lower triangular)
        float Li[DDIM][DDIM];
#pragma unroll
        for (int i = 0; i < DDIM; ++i)
#pragma unroll
            for (int j = 0; j < DDIM; ++j) Li[i][j] = 0.0f;
#pragma unroll
        for (int c = 0; c < DDIM; ++c) {
            Li[c][c] = 1.0f / L[c][c];
#pragma unroll
            for (int i = 0; i < DDIM; ++i) {
                if (i <= c) continue;
                float s = 0.0f;
#pragma unroll
                for (int m = 0; m < DDIM; ++m)
                    if (m >= c && m < i) s += L[i][m] * Li[m][c];
                Li[i][c] = -s / L[i][i];
            }
        }

        float hld = 0.0f;
#pragma unroll
        for (int i = 0; i < DDIM; ++i) hld += __logf(L[i][i]);

        // log_softmax(pi) denominator (redundant across lanes, tiny)
        float mx = pi[0];
#pragma unroll
        for (int j = 1; j < KCOMP; ++j) mx = fmaxf(mx, pi[j]);
        float ssum = 0.0f;
#pragma unroll
        for (int j = 0; j < KCOMP; ++j) ssum += __expf(pi[j] - mx);
        float lse = mx + __logf(ssum);

        const float LOG2PI = 1.83787706640934548356f;
        float constk = (pi[k] - lse) - hld - 0.5f * (float)DDIM * LOG2PI;

        const float r = 0.70710678118654752440f;  // 1/sqrt(2)
        float* c = g_tab + k * CSTRIDE;
        int idx = 0;
#pragma unroll
        for (int i = 0; i < DDIM; ++i)
#pragma unroll
            for (int j = 0; j < DDIM; ++j)
                if (j <= i) c[idx++] = Li[i][j] * r;
#pragma unroll
        for (int i = 0; i < DDIM; ++i) {
            float b = 0.0f;
#pragma unroll
            for (int j = 0; j < DDIM; ++j)
                if (j <= i) b += Li[i][j] * means[k * DDIM + j];
            c[36 + i] = -b * r;
        }
        sconst[k] = constk;
    }
    __syncthreads();
    if (k < KCOMP) {
        float Cmax = sconst[0];
#pragma unroll
        for (int j = 1; j < KCOMP; ++j) Cmax = fmaxf(Cmax, sconst[j]);
        float* c = g_tab + k * CSTRIDE;
        c[44] = sconst[k] - Cmax;  // pre-folded exp offset (<= 0)
        c[45] = Cmax;
        c[46] = 0.0f;
        c[47] = 0.0f;
    }
}

__global__ __launch_bounds__(256, 4) void gmm_eval(const float* __restrict__ x,
                                                   float* __restrict__ out, int n) {
    __shared__ float sc[KCOMP * CSTRIDE];

    {   // cooperative table load: 768 floats = 192 float4, coalesced, L2-hit
        const int t = threadIdx.x;
        if (t < (KCOMP * CSTRIDE) / 4)
            ((float4*)sc)[t] = ((const float4*)g_tab)[t];
    }
    __syncthreads();

    const float Cmax = sc[45];

    const int base = blockIdx.x * (256 * PPT) + threadIdx.x;
    float xv[PPT][DDIM];
#pragma unroll
    for (int p = 0; p < PPT; ++p) {
        int pt = base + p * 256;   // n = 1048576 = grid*256*PPT exactly
        const float4* xp = (const float4*)(x + (size_t)pt * DDIM);
        float4 a = xp[0];
        float4 b = xp[1];
        xv[p][0] = a.x; xv[p][1] = a.y; xv[p][2] = a.z; xv[p][3] = a.w;
        xv[p][4] = b.x; xv[p][5] = b.y; xv[p][6] = b.z; xv[p][7] = b.w;
    }

    float s[PPT];
#pragma unroll
    for (int p = 0; p < PPT; ++p) s[p] = 0.0f;

#pragma unroll 1
    for (int kk = 0; kk < KCOMP; ++kk) {
        const float4* c4 = (const float4*)(sc + kk * CSTRIDE);  // 16B-aligned, broadcast
        float cc[48];
#pragma unroll
        for (int t = 0; t < 12; ++t) {      // 12x ds_read_b128, uniform addr
            float4 v = c4[t];
            cc[4 * t + 0] = v.x; cc[4 * t + 1] = v.y;
            cc[4 * t + 2] = v.z; cc[4 * t + 3] = v.w;
        }
        const float ck = cc[44];            // already const_k - Cmax
#pragma unroll
        for (int p = 0; p < PPT; ++p) {
            float q = 0.0f;
            int idx = 0;
#pragma unroll
            for (int i = 0; i < DDIM; ++i) {
                float y = cc[36 + i];
#pragma unroll
                for (int j = 0; j <= i; ++j) { y = fmaf(cc[idx], xv[p][j], y); ++idx; }
                q = fmaf(y, y, q);
            }
            s[p] += __expf(ck - q);
        }
    }

#pragma unroll
    for (int p = 0; p < PPT; ++p) {
        int pt = base + p * 256;
        if (pt < n) out[pt] = Cmax + __logf(s[p]);
    }
}

extern "C" void kernel_launch(void* const* d_in, const int* in_sizes, int n_in,
                              void* d_out, int out_size, void* d_ws, size_t ws_size,
                              hipStream_t stream) {
    const float* x        = (const float*)d_in[0];
    const float* means    = (const float*)d_in[1];
    const float* chol_var = (const float*)d_in[2];
    const float* pi       = (const float*)d_in[3];
    float* out = (float*)d_out;
    (void)d_ws; (void)ws_size;

    int n = in_sizes[0] / DDIM;                    // 1048576

    gmm_setup<<<1, 64, 0, stream>>>(means, chol_var, pi);

    int nthreads = (n + PPT - 1) / PPT;            // 262144
    gmm_eval<<<(nthreads + 255) / 256, 256, 0, stream>>>(x, out, n);
}